// Round 1
// baseline (298.906 us; speedup 1.0000x reference)
//
#include <hip/hip_runtime.h>

// SpatialTransformer3D: B=2, H=W=D=128, C=4.
// image: (B,H,W,D,C) fp32; transformation: (B,H,W,D,3) fp32 in [0,1).
// out[b,i,j,k,:] = trilinear sample of image[b] at coords = t * grid,
// grid (xy-indexed meshgrid): gx = -1 + j*2/127, gy = -1 + i*2/127, gz = -1 + k*2/127.

__global__ __launch_bounds__(256) void st3d_kernel(
    const float* __restrict__ img,     // (B,128,128,128,4)
    const float* __restrict__ trans,   // (B,128,128,128,3)
    float4* __restrict__ out,          // (B,128,128,128,4) as float4
    int N)                             // B*128^3
{
    int idx = blockIdx.x * blockDim.x + threadIdx.x;
    if (idx >= N) return;

    // decompose: idx = ((b*128 + i)*128 + j)*128 + k   (i=H/y, j=W/x, k=D/z)
    int k = idx & 127;
    int j = (idx >> 7) & 127;
    int i = (idx >> 14) & 127;
    int b = idx >> 21;

    const float step = 2.0f / 127.0f;   // matches jnp.linspace(-1,1,128) delta
    float gx = -1.0f + step * (float)j;
    float gy = -1.0f + step * (float)i;
    float gz = -1.0f + step * (float)k;

    const float* t = trans + (size_t)idx * 3;
    float cx = t[0] * gx;
    float cy = t[1] * gy;
    float cz = t[2] * gz;

    // x = 0.5*(c+1)*128 — 0.5 and 128 are exact exponent shifts; only (c+1) rounds.
    float x = (cx + 1.0f) * 64.0f;
    float y = (cy + 1.0f) * 64.0f;
    float z = (cz + 1.0f) * 64.0f;

    int x0 = (int)floorf(x);
    int y0 = (int)floorf(y);
    int z0 = (int)floorf(z);
    int x1 = min(max(x0 + 1, 0), 127);
    int y1 = min(max(y0 + 1, 0), 127);
    int z1 = min(max(z0 + 1, 0), 127);
    x0 = min(max(x0, 0), 127);
    y0 = min(max(y0, 0), 127);
    z0 = min(max(z0, 0), 127);

    // weights use the CLIPPED upper corners (reference semantics)
    float dx = (float)x1 - x;
    float dy = (float)y1 - y;
    float dz = (float)z1 - z;
    float ex = 1.0f - dx;
    float ey = 1.0f - dy;
    float ez = 1.0f - dz;

    const float4* img4 = (const float4*)img;
    // corner float4 index: ((b*128 + y)*128 + x)*128 + z
    int base_b = b << 21;
    int ry0 = base_b + (y0 << 14);
    int ry1 = base_b + (y1 << 14);
    int cx0 = x0 << 7;
    int cx1 = x1 << 7;

    float4 c000 = img4[ry0 + cx0 + z0];
    float4 c100 = img4[ry1 + cx0 + z0];
    float4 c010 = img4[ry0 + cx1 + z0];
    float4 c110 = img4[ry1 + cx1 + z0];
    float4 c001 = img4[ry0 + cx0 + z1];
    float4 c101 = img4[ry1 + cx0 + z1];
    float4 c011 = img4[ry0 + cx1 + z1];
    float4 c111 = img4[ry1 + cx1 + z1];

    float w000 = dz * dx * dy;
    float w100 = dz * dx * ey;
    float w010 = dz * ex * dy;
    float w110 = dz * ex * ey;
    float w001 = ez * dx * dy;
    float w101 = ez * dx * ey;
    float w011 = ez * ex * dy;
    float w111 = ez * ex * ey;

    float4 o;
    o.x = w000*c000.x + w100*c100.x + w010*c010.x + w110*c110.x
        + w001*c001.x + w101*c101.x + w011*c011.x + w111*c111.x;
    o.y = w000*c000.y + w100*c100.y + w010*c010.y + w110*c110.y
        + w001*c001.y + w101*c101.y + w011*c011.y + w111*c111.y;
    o.z = w000*c000.z + w100*c100.z + w010*c010.z + w110*c110.z
        + w001*c001.z + w101*c101.z + w011*c011.z + w111*c111.z;
    o.w = w000*c000.w + w100*c100.w + w010*c010.w + w110*c110.w
        + w001*c001.w + w101*c101.w + w011*c011.w + w111*c111.w;

    out[idx] = o;
}

extern "C" void kernel_launch(void* const* d_in, const int* in_sizes, int n_in,
                              void* d_out, int out_size, void* d_ws, size_t ws_size,
                              hipStream_t stream) {
    const float* img   = (const float*)d_in[0];
    const float* trans = (const float*)d_in[1];
    float4* out = (float4*)d_out;

    int N = in_sizes[1] / 3;  // B*128^3 voxels
    int block = 256;
    int grid = (N + block - 1) / block;
    st3d_kernel<<<grid, block, 0, stream>>>(img, trans, out, N);
}